// Round 6
// baseline (255.994 us; speedup 1.0000x reference)
//
#include <hip/hip_runtime.h>
#include <math.h>

typedef __attribute__((ext_vector_type(4))) float f32x4;
typedef __attribute__((ext_vector_type(16))) float f32x16;
typedef __attribute__((ext_vector_type(8))) short bf16x8;
typedef __attribute__((ext_vector_type(4))) unsigned short us4;

#define T_SEQ 2048
#define NH 16
#define HD 64
#define CDIM 1024

__device__ __forceinline__ unsigned short f2bf(float f) {
  unsigned int u = __float_as_uint(f);
  u += 0x7fffu + ((u >> 16) & 1u);
  return (unsigned short)(u >> 16);
}

__device__ __forceinline__ f32x16 zero16() {
  f32x16 z;
#pragma unroll
  for (int i = 0; i < 16; ++i) z[i] = 0.0f;
  return z;
}

// global -> LDS direct (16B/lane, wave-uniform LDS base + lane*16)
#define GLOAD_LDS(g, l)                                                   \
  __builtin_amdgcn_global_load_lds(                                       \
      (const __attribute__((address_space(1))) unsigned int*)(g),         \
      (__attribute__((address_space(3))) unsigned int*)(l), 16, 0, 0)

// ---------------- cast x: fp32 -> bf16 ----------------
__global__ __launch_bounds__(256) void cast_x_kernel(const float* __restrict__ src,
                                                     unsigned short* __restrict__ dst,
                                                     int n4) {
  int i = blockIdx.x * 256 + threadIdx.x;
  if (i >= n4) return;
  f32x4 v = reinterpret_cast<const f32x4*>(src)[i];
  us4 o;
#pragma unroll
  for (int j = 0; j < 4; ++j) o[j] = f2bf(v[j]);
  reinterpret_cast<us4*>(dst)[i] = o;
}

// ------------- transpose + cast: W [K][N] fp32 -> W^T [N][K] bf16 -------------
__global__ __launch_bounds__(256) void transpose_cast_kernel(const float* __restrict__ src,
                                                             unsigned short* __restrict__ dst,
                                                             int ldsrc, int lddst) {
  __shared__ float tile[32][33];
  int n0 = blockIdx.x * 32, k0 = blockIdx.y * 32;
  int tx = threadIdx.x, ty = threadIdx.y;  // block (32,8)
#pragma unroll
  for (int r = 0; r < 4; ++r)
    tile[ty + r * 8][tx] = src[(size_t)(k0 + ty + r * 8) * ldsrc + n0 + tx];
  __syncthreads();
#pragma unroll
  for (int r = 0; r < 4; ++r)
    dst[(size_t)(n0 + ty + r * 8) * lddst + k0 + tx] = f2bf(tile[tx][ty + r * 8]);
}

// ---------------- RoPE table: cos/sin [T][32] fp32 ----------------
__global__ __launch_bounds__(256) void rope_table_kernel(float* __restrict__ cost,
                                                         float* __restrict__ sint) {
  int idx = blockIdx.x * 256 + threadIdx.x;  // 2048*32
  int t = idx >> 5, j = idx & 31;
  double invf = pow(10000.0, -(double)j / 32.0);
  double ang = (double)t * invf;
  cost[idx] = (float)cos(ang);
  sint[idx] = (float)sin(ang);
}

// ---------------- GEMM: C[M][N] = A[M][K] * B^T[N][K], bf16 in, fp32 acc ----
// m97 structure: 128x128 tile, BK=32, LINEAR LDS (no pad), staged via
// global_load_lds width=16 (2 A-chunks + 2 B-chunks per wave per K-step).
// MODE 1: qkv epilogue with RoPE; q/k/v stored in FRAGMENT-MAJOR layouts:
//   QF/KF[bh][blk32][ks][lane][8], VF[bh][t64][dgrp][ks][lane][8]
// MODE 0: plain fp32 store to out[M][N]
template <int MODE>
__global__ __launch_bounds__(256) void gemm_kernel(
    const unsigned short* __restrict__ A, const unsigned short* __restrict__ Bt,
    int M, int N, int K,
    unsigned short* __restrict__ qo, unsigned short* __restrict__ ko,
    unsigned short* __restrict__ vTo, const float* __restrict__ cost,
    const float* __restrict__ sint, float* __restrict__ out) {
  __shared__ __align__(16) unsigned short As[128 * 32];  // linear [row][32]
  __shared__ __align__(16) unsigned short Bs[128 * 32];
  const int tid = threadIdx.x;
  const int lane = tid & 63;
  const int wave = tid >> 6;
  const int wr = wave >> 1, wc = wave & 1;
  const int m0 = blockIdx.y * 128, n0 = blockIdx.x * 128;
  const int lrow = lane & 15, lhi = lane >> 4, lk8 = (lane >> 4) * 8;
  // staging decomposition: chunk c = 16 rows x 64B; lane covers row c*16+(lane>>2),
  // bytes (lane&3)*16 -> elements (lane&3)*8. LDS dest = chunk base + lane*16B.
  const int srow = lane >> 2, scol = (lane & 3) * 8;

  f32x4 zero4 = {0.f, 0.f, 0.f, 0.f};
  f32x4 acc[4][4];
#pragma unroll
  for (int mi = 0; mi < 4; ++mi)
#pragma unroll
    for (int ni = 0; ni < 4; ++ni) acc[mi][ni] = zero4;

  for (int kt = 0; kt < K; kt += 32) {
#pragma unroll
    for (int c2 = 0; c2 < 2; ++c2) {
      const int c = wave * 2 + c2;  // chunk 0..7
      GLOAD_LDS(&A[(size_t)(m0 + c * 16 + srow) * K + kt + scol], &As[c * 512]);
      GLOAD_LDS(&Bt[(size_t)(n0 + c * 16 + srow) * K + kt + scol], &Bs[c * 512]);
    }
    __syncthreads();  // drains vmcnt (global_load_lds) before frag reads
    bf16x8 af[4], bfv[4];
#pragma unroll
    for (int i = 0; i < 4; ++i) {
      af[i] = *reinterpret_cast<const bf16x8*>(&As[(wr * 64 + i * 16 + lrow) * 32 + lk8]);
      bfv[i] = *reinterpret_cast<const bf16x8*>(&Bs[(wc * 64 + i * 16 + lrow) * 32 + lk8]);
    }
#pragma unroll
    for (int mi = 0; mi < 4; ++mi)
#pragma unroll
      for (int ni = 0; ni < 4; ++ni)
        acc[mi][ni] =
            __builtin_amdgcn_mfma_f32_16x16x32_bf16(af[mi], bfv[ni], acc[mi][ni], 0, 0, 0);
    __syncthreads();  // all reads done before next stage overwrites
  }

  if (MODE == 0) {
#pragma unroll
    for (int mi = 0; mi < 4; ++mi)
#pragma unroll
      for (int ni = 0; ni < 4; ++ni) {
        int n = n0 + wc * 64 + ni * 16 + lrow;
#pragma unroll
        for (int r = 0; r < 4; ++r) {
          int m = m0 + wr * 64 + mi * 16 + lhi * 4 + r;
          out[(size_t)m * N + n] = acc[mi][ni][r];
        }
      }
  } else {
#pragma unroll
    for (int mi = 0; mi < 4; ++mi) {
      int mb = m0 + wr * 64 + mi * 16 + lhi * 4;  // 4 consecutive rows (t)
      int b = mb >> 11, tb = mb & (T_SEQ - 1);
#pragma unroll
      for (int ni = 0; ni < 4; ++ni) {
        int n = n0 + wc * 64 + ni * 16 + lrow;
        int sec = n >> 10;          // 0=q 1=k 2=v
        int h = (n >> 6) & 15;
        int d = n & 63;
        int bh_ = b * NH + h;
        if (sec == 2) {
          // VF[bh][t64][dgrp][ks][lane][8], us4 over t=tb..tb+3 (e contiguous)
          int t64 = tb >> 6, ks = (tb >> 4) & 3, hiv = (tb >> 3) & 1, e0 = tb & 7;
          int dgrp = d >> 5, lanev = hiv * 32 + (d & 31);
          us4 pk;
#pragma unroll
          for (int r = 0; r < 4; ++r) pk[r] = f2bf(acc[mi][ni][r]);
          size_t addr =
              ((((size_t)bh_ * 32 + t64) * 2 + dgrp) * 4 + ks) * 512 + lanev * 8 + e0;
          *reinterpret_cast<us4*>(&vTo[addr]) = pk;
        } else {
          int dm = d & 31;
          float sgn = (d < 32) ? -1.0f : 1.0f;
          unsigned short* dstp = (sec == 0) ? qo : ko;
          int ks = d >> 4, hiq = (d >> 3) & 1, e = d & 7;
#pragma unroll
          for (int r = 0; r < 4; ++r) {
            int t = tb + r;
            float c = cost[t * 32 + dm], s = sint[t * 32 + dm];
            float val = acc[mi][ni][r] * c + sgn * acc[mi][ni ^ 2][r] * s;
            if (sec == 0) val *= 0.125f;  // 1/sqrt(64) folded into q
            int blk = t >> 5, lane_ = hiq * 32 + (t & 31);
            dstp[(((size_t)bh_ * 64 + blk) * 4 + ks) * 512 + lane_ * 8 + e] = f2bf(val);
          }
        }
      }
    }
  }
}

// ---------------- flash attention, causal; 32x32 swapped-QK^T ----------------
// Equal-work blocks: block j in head takes wave q-positions {j, 31-j, 32+j,
// 63-j} (sum of tile counts is constant) -> all 1024 blocks identical work,
// 4 blocks/CU resident throughout. Fragment-major K/Q/V loads (coalesced).
// In-register softmax, per-lane scalars; T13 defer-max skips O-rescale when
// max grows < 8; s_setprio(1) around MFMA clusters.
__global__ __launch_bounds__(256, 4) void attn_kernel(const unsigned short* __restrict__ qg,
                                                      const unsigned short* __restrict__ kg,
                                                      const unsigned short* __restrict__ vtg,
                                                      unsigned short* __restrict__ att) {
  __shared__ __align__(16) unsigned short P[4][32][72];  // per-wave P buffer
  const int tid = threadIdx.x;
  const int lane = tid & 63;
  const int w = tid >> 6;
  const int l31 = lane & 31, hi = lane >> 5;
  // bid -> (head, block j): xcd = bid&7 owns heads xcd*8..xcd*8+7
  const int bid = (int)blockIdx.x;
  const int xcd = bid & 7, j = bid >> 3;
  const int bh = xcd * 8 + (j >> 4);
  const int jq = j & 15;
  // equal-work wave position: {jq, 31-jq, 32+jq, 63-jq}
  const int pos = (w == 0) ? jq : (w == 1) ? (31 - jq) : (w == 2) ? (32 + jq) : (63 - jq);
  const int wq0 = pos * 32;
  const int qrow = wq0 + l31;  // this lane's query row
  const unsigned short* qfp = qg + (size_t)bh * 131072;
  const unsigned short* kfp = kg + (size_t)bh * 131072;
  const unsigned short* vfp = vtg + (size_t)bh * 131072;

  bf16x8 qf[4];  // QF[bh][pos][ks][lane]
#pragma unroll
  for (int ks = 0; ks < 4; ++ks)
    qf[ks] = *reinterpret_cast<const bf16x8*>(&qfp[((size_t)pos * 4 + ks) * 512 + lane * 8]);

  f32x16 oA = zero16(), oB = zero16();  // O^T: rows d 0-31 / 32-63, col = qrow
  float mrun = -3.0e38f, lrun = 0.0f;

  const int myt = ((wq0 + 31) >> 6) + 1;
  for (int t = 0; t < myt; ++t) {
    const int kvb = t * 64;
    // ---- coalesced fragment loads: K tile (2 blk32 groups) + V tile ----
    bf16x8 kfa[4], kfb[4], vfa[4], vfb[4];
#pragma unroll
    for (int ks = 0; ks < 4; ++ks) {
      kfa[ks] = *reinterpret_cast<const bf16x8*>(
          &kfp[((size_t)(2 * t) * 4 + ks) * 512 + lane * 8]);
      kfb[ks] = *reinterpret_cast<const bf16x8*>(
          &kfp[((size_t)(2 * t + 1) * 4 + ks) * 512 + lane * 8]);
      vfa[ks] = *reinterpret_cast<const bf16x8*>(
          &vfp[((size_t)(2 * t) * 4 + ks) * 512 + lane * 8]);
      vfb[ks] = *reinterpret_cast<const bf16x8*>(
          &vfp[((size_t)(2 * t + 1) * 4 + ks) * 512 + lane * 8]);
    }
    // ---- QK^T (swapped): S^T rows = keys, col = qrow ----
    f32x16 sA = zero16(), sB = zero16();
    __builtin_amdgcn_s_setprio(1);
#pragma unroll
    for (int ks = 0; ks < 4; ++ks) {
      sA = __builtin_amdgcn_mfma_f32_32x32x16_bf16(kfa[ks], qf[ks], sA, 0, 0, 0);
      sB = __builtin_amdgcn_mfma_f32_32x32x16_bf16(kfb[ks], qf[ks], sB, 0, 0, 0);
    }
    __builtin_amdgcn_s_setprio(0);
    // ---- causal mask (only final tile can contain future keys) ----
    if (t == myt - 1) {
#pragma unroll
      for (int r = 0; r < 16; ++r) {
        int keyA = kvb + (r & 3) + 8 * (r >> 2) + 4 * hi;
        if (keyA > qrow) sA[r] = -1e30f;
        if (keyA + 32 > qrow) sB[r] = -1e30f;
      }
    }
    // ---- in-register online softmax (per-lane scalars) ----
    float tr[16];
#pragma unroll
    for (int i = 0; i < 16; ++i) tr[i] = fmaxf(sA[i], sB[i]);
#pragma unroll
    for (int i = 0; i < 8; ++i) tr[i] = fmaxf(tr[i], tr[i + 8]);
#pragma unroll
    for (int i = 0; i < 4; ++i) tr[i] = fmaxf(tr[i], tr[i + 4]);
    float tm = fmaxf(fmaxf(tr[0], tr[1]), fmaxf(tr[2], tr[3]));
    tm = fmaxf(tm, __shfl_xor(tm, 32));  // merge lane halves (same query)
    // T13 defer-max: only rescale when max grew by > 8
    if (!__all(tm - mrun <= 8.0f)) {
      float mnew = fmaxf(mrun, tm);
      float alpha = __expf(mrun - mnew);
      lrun *= alpha;
#pragma unroll
      for (int i = 0; i < 16; ++i) {
        oA[i] *= alpha;
        oB[i] *= alpha;
      }
      mrun = mnew;
    }
#pragma unroll
    for (int i = 0; i < 16; ++i) {
      sA[i] = __expf(sA[i] - mrun);
      sB[i] = __expf(sB[i] - mrun);
    }
    float sr[16];
#pragma unroll
    for (int i = 0; i < 16; ++i) sr[i] = sA[i] + sB[i];
#pragma unroll
    for (int i = 0; i < 8; ++i) sr[i] += sr[i + 8];
#pragma unroll
    for (int i = 0; i < 4; ++i) sr[i] += sr[i + 4];
    float lsum = (sr[0] + sr[1]) + (sr[2] + sr[3]);
    lsum += __shfl_xor(lsum, 32);
    lrun += lsum;
    // ---- P: S-layout -> [q][key] in LDS (per-wave, no barrier) ----
#pragma unroll
    for (int g = 0; g < 4; ++g) {
      us4 pa, pb;
#pragma unroll
      for (int jj = 0; jj < 4; ++jj) {
        pa[jj] = f2bf(sA[4 * g + jj]);
        pb[jj] = f2bf(sB[4 * g + jj]);
      }
      *reinterpret_cast<us4*>(&P[w][l31][g * 8 + 4 * hi]) = pa;
      *reinterpret_cast<us4*>(&P[w][l31][32 + g * 8 + 4 * hi]) = pb;
    }
    // ---- PV: O^T += mfma(V^T, P) ----
    __builtin_amdgcn_s_setprio(1);
#pragma unroll
    for (int ks = 0; ks < 4; ++ks) {
      bf16x8 pf = *reinterpret_cast<const bf16x8*>(&P[w][l31][ks * 16 + hi * 8]);
      oA = __builtin_amdgcn_mfma_f32_32x32x16_bf16(vfa[ks], pf, oA, 0, 0, 0);
      oB = __builtin_amdgcn_mfma_f32_32x32x16_bf16(vfb[ks], pf, oB, 0, 0, 0);
    }
    __builtin_amdgcn_s_setprio(0);
  }

  const int b = bh >> 4, h = bh & 15;
  const float inv = 1.0f / lrun;
  const size_t obase = ((size_t)b * T_SEQ + qrow) * CDIM + h * HD;
#pragma unroll
  for (int g = 0; g < 4; ++g) {
    us4 pa, pb;
#pragma unroll
    for (int jj = 0; jj < 4; ++jj) {
      pa[jj] = f2bf(oA[4 * g + jj] * inv);
      pb[jj] = f2bf(oB[4 * g + jj] * inv);
    }
    *reinterpret_cast<us4*>(&att[obase + g * 8 + 4 * hi]) = pa;
    *reinterpret_cast<us4*>(&att[obase + 32 + g * 8 + 4 * hi]) = pb;
  }
}

extern "C" void kernel_launch(void* const* d_in, const int* in_sizes, int n_in,
                              void* d_out, int out_size, void* d_ws, size_t ws_size,
                              hipStream_t stream) {
  const float* x = (const float*)d_in[0];
  const float* Wq = (const float*)d_in[1];
  const float* Wkv = (const float*)d_in[2];
  const float* Wc = (const float*)d_in[3];
  float* out = (float*)d_out;

  char* ws = (char*)d_ws;
  size_t off = 0;
  auto alloc = [&](size_t bytes) {
    void* p = ws + off;
    off += (bytes + 255) & ~(size_t)255;
    return p;
  };
  const size_t NTOK = 4ull * T_SEQ;            // 8192
  const size_t NELEM = NTOK * CDIM;            // 8388608
  unsigned short* xb = (unsigned short*)alloc(NELEM * 2);   // also reused for att
  unsigned short* WT = (unsigned short*)alloc(3072ull * 1024 * 2);
  unsigned short* WcT = (unsigned short*)alloc(1024ull * 1024 * 2);
  unsigned short* qb = (unsigned short*)alloc(NELEM * 2);
  unsigned short* kb = (unsigned short*)alloc(NELEM * 2);
  unsigned short* vT = (unsigned short*)alloc(NELEM * 2);
  float* cost = (float*)alloc(T_SEQ * 32 * 4);
  float* sint = (float*)alloc(T_SEQ * 32 * 4);
  unsigned short* att = xb;  // xb dead after gemm<1>; reuse for attention output

  cast_x_kernel<<<(int)(NELEM / 4 / 256), 256, 0, stream>>>(x, xb, (int)(NELEM / 4));
  transpose_cast_kernel<<<dim3(32, 32), dim3(32, 8), 0, stream>>>(Wq, WT, 1024, 1024);
  transpose_cast_kernel<<<dim3(64, 32), dim3(32, 8), 0, stream>>>(Wkv, WT + 1024 * 1024, 2048,
                                                                  1024);
  transpose_cast_kernel<<<dim3(32, 32), dim3(32, 8), 0, stream>>>(Wc, WcT, 1024, 1024);
  rope_table_kernel<<<T_SEQ * 32 / 256, 256, 0, stream>>>(cost, sint);

  gemm_kernel<1><<<dim3(3072 / 128, NTOK / 128), 256, 0, stream>>>(
      xb, WT, (int)NTOK, 3072, 1024, qb, kb, vT, cost, sint, nullptr);

  attn_kernel<<<dim3(16 * 64), 256, 0, stream>>>(qb, kb, vT, att);

  gemm_kernel<0><<<dim3(1024 / 128, NTOK / 128), 256, 0, stream>>>(
      att, WcT, (int)NTOK, 1024, 1024, nullptr, nullptr, nullptr, nullptr, nullptr, out);
}

// Round 7
// 201.736 us; speedup vs baseline: 1.2690x; 1.2690x over previous
//
#include <hip/hip_runtime.h>
#include <math.h>

typedef __attribute__((ext_vector_type(4))) float f32x4;
typedef __attribute__((ext_vector_type(16))) float f32x16;
typedef __attribute__((ext_vector_type(8))) short bf16x8;
typedef __attribute__((ext_vector_type(4))) unsigned short us4;

#define T_SEQ 2048
#define NH 16
#define HD 64
#define CDIM 1024

__device__ __forceinline__ unsigned short f2bf(float f) {
  unsigned int u = __float_as_uint(f);
  u += 0x7fffu + ((u >> 16) & 1u);
  return (unsigned short)(u >> 16);
}

__device__ __forceinline__ f32x16 zero16() {
  f32x16 z;
#pragma unroll
  for (int i = 0; i < 16; ++i) z[i] = 0.0f;
  return z;
}

// global -> LDS direct (16B/lane, wave-uniform LDS base + lane*16)
#define GLOAD_LDS(g, l)                                                   \
  __builtin_amdgcn_global_load_lds(                                       \
      (const __attribute__((address_space(1))) unsigned int*)(g),         \
      (__attribute__((address_space(3))) unsigned int*)(l), 16, 0, 0)

// ---------------- cast x: fp32 -> bf16 ----------------
__global__ __launch_bounds__(256) void cast_x_kernel(const float* __restrict__ src,
                                                     unsigned short* __restrict__ dst,
                                                     int n4) {
  int i = blockIdx.x * 256 + threadIdx.x;
  if (i >= n4) return;
  f32x4 v = reinterpret_cast<const f32x4*>(src)[i];
  us4 o;
#pragma unroll
  for (int j = 0; j < 4; ++j) o[j] = f2bf(v[j]);
  reinterpret_cast<us4*>(dst)[i] = o;
}

// ------------- transpose + cast: W [K][N] fp32 -> W^T [N][K] bf16 -------------
__global__ __launch_bounds__(256) void transpose_cast_kernel(const float* __restrict__ src,
                                                             unsigned short* __restrict__ dst,
                                                             int ldsrc, int lddst) {
  __shared__ float tile[32][33];
  int n0 = blockIdx.x * 32, k0 = blockIdx.y * 32;
  int tx = threadIdx.x, ty = threadIdx.y;  // block (32,8)
#pragma unroll
  for (int r = 0; r < 4; ++r)
    tile[ty + r * 8][tx] = src[(size_t)(k0 + ty + r * 8) * ldsrc + n0 + tx];
  __syncthreads();
#pragma unroll
  for (int r = 0; r < 4; ++r)
    dst[(size_t)(n0 + ty + r * 8) * lddst + k0 + tx] = f2bf(tile[tx][ty + r * 8]);
}

// ---------------- RoPE table: cos/sin [T][32] fp32 ----------------
__global__ __launch_bounds__(256) void rope_table_kernel(float* __restrict__ cost,
                                                         float* __restrict__ sint) {
  int idx = blockIdx.x * 256 + threadIdx.x;  // 2048*32
  int t = idx >> 5, j = idx & 31;
  double invf = pow(10000.0, -(double)j / 32.0);
  double ang = (double)t * invf;
  cost[idx] = (float)cos(ang);
  sint[idx] = (float)sin(ang);
}

// ---------------- GEMM: C[M][N] = A[M][K] * B^T[N][K], bf16 in, fp32 acc ----
// m97 structure: 128x128 tile, BK=32, LINEAR LDS (no pad), staged via
// global_load_lds width=16. MODE 1: qkv epilogue with RoPE, fragment-major
// outputs QF/KF[bh][blk32][ks][lane][8], VF[bh][t64][dgrp][ks][lane][8].
// MODE 0: plain fp32 store to out[M][N].
template <int MODE>
__global__ __launch_bounds__(256) void gemm_kernel(
    const unsigned short* __restrict__ A, const unsigned short* __restrict__ Bt,
    int M, int N, int K,
    unsigned short* __restrict__ qo, unsigned short* __restrict__ ko,
    unsigned short* __restrict__ vTo, const float* __restrict__ cost,
    const float* __restrict__ sint, float* __restrict__ out) {
  __shared__ __align__(16) unsigned short As[128 * 32];  // linear [row][32]
  __shared__ __align__(16) unsigned short Bs[128 * 32];
  const int tid = threadIdx.x;
  const int lane = tid & 63;
  const int wave = tid >> 6;
  const int wr = wave >> 1, wc = wave & 1;
  const int m0 = blockIdx.y * 128, n0 = blockIdx.x * 128;
  const int lrow = lane & 15, lhi = lane >> 4, lk8 = (lane >> 4) * 8;
  const int srow = lane >> 2, scol = (lane & 3) * 8;

  f32x4 zero4 = {0.f, 0.f, 0.f, 0.f};
  f32x4 acc[4][4];
#pragma unroll
  for (int mi = 0; mi < 4; ++mi)
#pragma unroll
    for (int ni = 0; ni < 4; ++ni) acc[mi][ni] = zero4;

  for (int kt = 0; kt < K; kt += 32) {
#pragma unroll
    for (int c2 = 0; c2 < 2; ++c2) {
      const int c = wave * 2 + c2;  // chunk 0..7
      GLOAD_LDS(&A[(size_t)(m0 + c * 16 + srow) * K + kt + scol], &As[c * 512]);
      GLOAD_LDS(&Bt[(size_t)(n0 + c * 16 + srow) * K + kt + scol], &Bs[c * 512]);
    }
    __syncthreads();  // drains vmcnt (global_load_lds) before frag reads
    bf16x8 af[4], bfv[4];
#pragma unroll
    for (int i = 0; i < 4; ++i) {
      af[i] = *reinterpret_cast<const bf16x8*>(&As[(wr * 64 + i * 16 + lrow) * 32 + lk8]);
      bfv[i] = *reinterpret_cast<const bf16x8*>(&Bs[(wc * 64 + i * 16 + lrow) * 32 + lk8]);
    }
#pragma unroll
    for (int mi = 0; mi < 4; ++mi)
#pragma unroll
      for (int ni = 0; ni < 4; ++ni)
        acc[mi][ni] =
            __builtin_amdgcn_mfma_f32_16x16x32_bf16(af[mi], bfv[ni], acc[mi][ni], 0, 0, 0);
    __syncthreads();  // all reads done before next stage overwrites
  }

  if (MODE == 0) {
#pragma unroll
    for (int mi = 0; mi < 4; ++mi)
#pragma unroll
      for (int ni = 0; ni < 4; ++ni) {
        int n = n0 + wc * 64 + ni * 16 + lrow;
#pragma unroll
        for (int r = 0; r < 4; ++r) {
          int m = m0 + wr * 64 + mi * 16 + lhi * 4 + r;
          out[(size_t)m * N + n] = acc[mi][ni][r];
        }
      }
  } else {
#pragma unroll
    for (int mi = 0; mi < 4; ++mi) {
      int mb = m0 + wr * 64 + mi * 16 + lhi * 4;  // 4 consecutive rows (t)
      int b = mb >> 11, tb = mb & (T_SEQ - 1);
#pragma unroll
      for (int ni = 0; ni < 4; ++ni) {
        int n = n0 + wc * 64 + ni * 16 + lrow;
        int sec = n >> 10;          // 0=q 1=k 2=v
        int h = (n >> 6) & 15;
        int d = n & 63;
        int bh_ = b * NH + h;
        if (sec == 2) {
          int t64 = tb >> 6, ks = (tb >> 4) & 3, hiv = (tb >> 3) & 1, e0 = tb & 7;
          int dgrp = d >> 5, lanev = hiv * 32 + (d & 31);
          us4 pk;
#pragma unroll
          for (int r = 0; r < 4; ++r) pk[r] = f2bf(acc[mi][ni][r]);
          size_t addr =
              ((((size_t)bh_ * 32 + t64) * 2 + dgrp) * 4 + ks) * 512 + lanev * 8 + e0;
          *reinterpret_cast<us4*>(&vTo[addr]) = pk;
        } else {
          int dm = d & 31;
          float sgn = (d < 32) ? -1.0f : 1.0f;
          unsigned short* dstp = (sec == 0) ? qo : ko;
          int ks = d >> 4, hiq = (d >> 3) & 1, e = d & 7;
#pragma unroll
          for (int r = 0; r < 4; ++r) {
            int t = tb + r;
            float c = cost[t * 32 + dm], s = sint[t * 32 + dm];
            float val = acc[mi][ni][r] * c + sgn * acc[mi][ni ^ 2][r] * s;
            if (sec == 0) val *= 0.125f;  // 1/sqrt(64) folded into q
            int blk = t >> 5, lane_ = hiq * 32 + (t & 31);
            dstp[(((size_t)bh_ * 64 + blk) * 4 + ks) * 512 + lane_ * 8 + e] = f2bf(val);
          }
        }
      }
    }
  }
}

// ---------------- flash attention, causal; 32x32 swapped-QK^T ----------------
// EXACT per-wave balance: wave owns q-blocks {p, 63-p}; myt(pos)=pos/2+1 so
// every wave processes exactly 33 kv-tiles -> no drain tail. 512 blocks
// (2/CU, 8 waves/CU), all resident start-to-finish. Register double-buffered
// K prefetch (next K issued during softmax/PV) + early V issue (consumed
// after softmax) hide L2/L3 latency. Fragment-major layouts (coalesced).
// In-register softmax; T13 defer-max; setprio around MFMA clusters.
__global__ __launch_bounds__(256, 2) void attn_kernel(const unsigned short* __restrict__ qg,
                                                      const unsigned short* __restrict__ kg,
                                                      const unsigned short* __restrict__ vtg,
                                                      unsigned short* __restrict__ att) {
  __shared__ __align__(16) unsigned short P[4][32][72];  // per-wave P buffer
  const int tid = threadIdx.x;
  const int lane = tid & 63;
  const int w = tid >> 6;
  const int l31 = lane & 31, hi = lane >> 5;
  // bid -> (head, pair group): xcd = bid&7 owns heads xcd*8..xcd*8+7
  const int bid = (int)blockIdx.x;
  const int xcd = bid & 7, j = bid >> 3;        // j 0..63
  const int bh = xcd * 8 + (j >> 3);            // 8 blocks per head
  const int p = (j & 7) * 4 + w;                // pair index 0..31
  const unsigned short* qfp = qg + (size_t)bh * 131072;
  const unsigned short* kfp = kg + (size_t)bh * 131072;
  const unsigned short* vfp = vtg + (size_t)bh * 131072;
  const int b = bh >> 4, h = bh & 15;

  auto run_pos = [&](int pos) {
    const int qrow = pos * 32 + l31;
    bf16x8 qf[4];
#pragma unroll
    for (int ks = 0; ks < 4; ++ks)
      qf[ks] =
          *reinterpret_cast<const bf16x8*>(&qfp[((size_t)pos * 4 + ks) * 512 + lane * 8]);
    f32x16 oA = zero16(), oB = zero16();
    float mrun = -3.0e38f, lrun = 0.0f;
    const int myt = (pos >> 1) + 1;

    bf16x8 kA0[4], kB0[4], kA1[4], kB1[4];
#pragma unroll
    for (int ks = 0; ks < 4; ++ks) {  // preload K tile 0
      kA0[ks] = *reinterpret_cast<const bf16x8*>(&kfp[(size_t)(0 + ks) * 512 + lane * 8]);
      kB0[ks] = *reinterpret_cast<const bf16x8*>(&kfp[(size_t)(4 + ks) * 512 + lane * 8]);
    }

    auto step = [&](int t, bf16x8 (&kcA)[4], bf16x8 (&kcB)[4], bf16x8 (&knA)[4],
                    bf16x8 (&knB)[4]) {
      // early V issue: consumed only after softmax -> latency hidden
      bf16x8 vA[4], vB[4];
#pragma unroll
      for (int ks = 0; ks < 4; ++ks) {
        vA[ks] = *reinterpret_cast<const bf16x8*>(
            &vfp[((size_t)(2 * t) * 4 + ks) * 512 + lane * 8]);
        vB[ks] = *reinterpret_cast<const bf16x8*>(
            &vfp[((size_t)(2 * t + 1) * 4 + ks) * 512 + lane * 8]);
      }
      // QK^T with current K (prefetched last iteration)
      f32x16 sA = zero16(), sB = zero16();
      __builtin_amdgcn_s_setprio(1);
#pragma unroll
      for (int ks = 0; ks < 4; ++ks) {
        sA = __builtin_amdgcn_mfma_f32_32x32x16_bf16(kcA[ks], qf[ks], sA, 0, 0, 0);
        sB = __builtin_amdgcn_mfma_f32_32x32x16_bf16(kcB[ks], qf[ks], sB, 0, 0, 0);
      }
      __builtin_amdgcn_s_setprio(0);
      // prefetch next K tile (used next iteration; hides under softmax+PV)
      if (t + 1 < myt) {
#pragma unroll
        for (int ks = 0; ks < 4; ++ks) {
          knA[ks] = *reinterpret_cast<const bf16x8*>(
              &kfp[((size_t)(2 * t + 2) * 4 + ks) * 512 + lane * 8]);
          knB[ks] = *reinterpret_cast<const bf16x8*>(
              &kfp[((size_t)(2 * t + 3) * 4 + ks) * 512 + lane * 8]);
        }
      }
      // causal mask (only final tile can contain future keys)
      if (t == myt - 1) {
        const int kvb = t * 64;
#pragma unroll
        for (int r = 0; r < 16; ++r) {
          int keyA = kvb + (r & 3) + 8 * (r >> 2) + 4 * hi;
          if (keyA > qrow) sA[r] = -1e30f;
          if (keyA + 32 > qrow) sB[r] = -1e30f;
        }
      }
      // in-register online softmax (per-lane scalars)
      float tr[16];
#pragma unroll
      for (int i = 0; i < 16; ++i) tr[i] = fmaxf(sA[i], sB[i]);
#pragma unroll
      for (int i = 0; i < 8; ++i) tr[i] = fmaxf(tr[i], tr[i + 8]);
#pragma unroll
      for (int i = 0; i < 4; ++i) tr[i] = fmaxf(tr[i], tr[i + 4]);
      float tm = fmaxf(fmaxf(tr[0], tr[1]), fmaxf(tr[2], tr[3]));
      tm = fmaxf(tm, __shfl_xor(tm, 32));  // merge lane halves (same query)
      // T13 defer-max: only rescale when max grew by > 8
      if (!__all(tm - mrun <= 8.0f)) {
        float mnew = fmaxf(mrun, tm);
        float alpha = __expf(mrun - mnew);
        lrun *= alpha;
#pragma unroll
        for (int i = 0; i < 16; ++i) {
          oA[i] *= alpha;
          oB[i] *= alpha;
        }
        mrun = mnew;
      }
#pragma unroll
      for (int i = 0; i < 16; ++i) {
        sA[i] = __expf(sA[i] - mrun);
        sB[i] = __expf(sB[i] - mrun);
      }
      float sr[16];
#pragma unroll
      for (int i = 0; i < 16; ++i) sr[i] = sA[i] + sB[i];
#pragma unroll
      for (int i = 0; i < 8; ++i) sr[i] += sr[i + 8];
#pragma unroll
      for (int i = 0; i < 4; ++i) sr[i] += sr[i + 4];
      float lsum = (sr[0] + sr[1]) + (sr[2] + sr[3]);
      lsum += __shfl_xor(lsum, 32);
      lrun += lsum;
      // P: S-layout -> [q][key] via per-wave LDS (no barrier needed)
#pragma unroll
      for (int g = 0; g < 4; ++g) {
        us4 pa, pb;
#pragma unroll
        for (int jj = 0; jj < 4; ++jj) {
          pa[jj] = f2bf(sA[4 * g + jj]);
          pb[jj] = f2bf(sB[4 * g + jj]);
        }
        *reinterpret_cast<us4*>(&P[w][l31][g * 8 + 4 * hi]) = pa;
        *reinterpret_cast<us4*>(&P[w][l31][32 + g * 8 + 4 * hi]) = pb;
      }
      // PV: O^T += mfma(V^T, P)
      __builtin_amdgcn_s_setprio(1);
#pragma unroll
      for (int ks = 0; ks < 4; ++ks) {
        bf16x8 pf = *reinterpret_cast<const bf16x8*>(&P[w][l31][ks * 16 + hi * 8]);
        oA = __builtin_amdgcn_mfma_f32_32x32x16_bf16(vA[ks], pf, oA, 0, 0, 0);
        oB = __builtin_amdgcn_mfma_f32_32x32x16_bf16(vB[ks], pf, oB, 0, 0, 0);
      }
      __builtin_amdgcn_s_setprio(0);
    };

    int t = 0;
    while (t < myt) {
      step(t, kA0, kB0, kA1, kB1);
      ++t;
      if (t >= myt) break;
      step(t, kA1, kB1, kA0, kB0);
      ++t;
    }

    const float inv = 1.0f / lrun;
    const size_t obase = ((size_t)b * T_SEQ + qrow) * CDIM + h * HD;
#pragma unroll
    for (int g = 0; g < 4; ++g) {
      us4 pa, pb;
#pragma unroll
      for (int jj = 0; jj < 4; ++jj) {
        pa[jj] = f2bf(oA[4 * g + jj] * inv);
        pb[jj] = f2bf(oB[4 * g + jj] * inv);
      }
      *reinterpret_cast<us4*>(&att[obase + g * 8 + 4 * hi]) = pa;
      *reinterpret_cast<us4*>(&att[obase + 32 + g * 8 + 4 * hi]) = pb;
    }
  };

  run_pos(63 - p);  // heavy half first (streams K/V, warms L2 for light half)
  run_pos(p);       // light half re-reads an L2-hot prefix
}

extern "C" void kernel_launch(void* const* d_in, const int* in_sizes, int n_in,
                              void* d_out, int out_size, void* d_ws, size_t ws_size,
                              hipStream_t stream) {
  const float* x = (const float*)d_in[0];
  const float* Wq = (const float*)d_in[1];
  const float* Wkv = (const float*)d_in[2];
  const float* Wc = (const float*)d_in[3];
  float* out = (float*)d_out;

  char* ws = (char*)d_ws;
  size_t off = 0;
  auto alloc = [&](size_t bytes) {
    void* p = ws + off;
    off += (bytes + 255) & ~(size_t)255;
    return p;
  };
  const size_t NTOK = 4ull * T_SEQ;            // 8192
  const size_t NELEM = NTOK * CDIM;            // 8388608
  unsigned short* xb = (unsigned short*)alloc(NELEM * 2);   // also reused for att
  unsigned short* WT = (unsigned short*)alloc(3072ull * 1024 * 2);
  unsigned short* WcT = (unsigned short*)alloc(1024ull * 1024 * 2);
  unsigned short* qb = (unsigned short*)alloc(NELEM * 2);
  unsigned short* kb = (unsigned short*)alloc(NELEM * 2);
  unsigned short* vT = (unsigned short*)alloc(NELEM * 2);
  float* cost = (float*)alloc(T_SEQ * 32 * 4);
  float* sint = (float*)alloc(T_SEQ * 32 * 4);
  unsigned short* att = xb;  // xb dead after gemm<1>; reuse for attention output

  cast_x_kernel<<<(int)(NELEM / 4 / 256), 256, 0, stream>>>(x, xb, (int)(NELEM / 4));
  transpose_cast_kernel<<<dim3(32, 32), dim3(32, 8), 0, stream>>>(Wq, WT, 1024, 1024);
  transpose_cast_kernel<<<dim3(64, 32), dim3(32, 8), 0, stream>>>(Wkv, WT + 1024 * 1024, 2048,
                                                                  1024);
  transpose_cast_kernel<<<dim3(32, 32), dim3(32, 8), 0, stream>>>(Wc, WcT, 1024, 1024);
  rope_table_kernel<<<T_SEQ * 32 / 256, 256, 0, stream>>>(cost, sint);

  gemm_kernel<1><<<dim3(3072 / 128, NTOK / 128), 256, 0, stream>>>(
      xb, WT, (int)NTOK, 3072, 1024, qb, kb, vT, cost, sint, nullptr);

  attn_kernel<<<dim3(512), 256, 0, stream>>>(qb, kb, vT, att);

  gemm_kernel<0><<<dim3(1024 / 128, NTOK / 128), 256, 0, stream>>>(
      att, WcT, (int)NTOK, 1024, 1024, nullptr, nullptr, nullptr, nullptr, nullptr, out);
}

// Round 8
// 188.191 us; speedup vs baseline: 1.3603x; 1.0720x over previous
//
#include <hip/hip_runtime.h>
#include <math.h>

typedef __attribute__((ext_vector_type(4))) float f32x4;
typedef __attribute__((ext_vector_type(16))) float f32x16;
typedef __attribute__((ext_vector_type(8))) short bf16x8;
typedef __attribute__((ext_vector_type(4))) unsigned short us4;

#define T_SEQ 2048
#define NH 16
#define HD 64
#define CDIM 1024

__device__ __forceinline__ unsigned short f2bf(float f) {
  unsigned int u = __float_as_uint(f);
  u += 0x7fffu + ((u >> 16) & 1u);
  return (unsigned short)(u >> 16);
}

__device__ __forceinline__ f32x16 zero16() {
  f32x16 z;
#pragma unroll
  for (int i = 0; i < 16; ++i) z[i] = 0.0f;
  return z;
}

// global -> LDS direct (16B/lane, wave-uniform LDS base + lane*16)
#define GLOAD_LDS(g, l)                                                   \
  __builtin_amdgcn_global_load_lds(                                       \
      (const __attribute__((address_space(1))) unsigned int*)(g),         \
      (__attribute__((address_space(3))) unsigned int*)(l), 16, 0, 0)

// ---------------- cast x: fp32 -> bf16 ----------------
__global__ __launch_bounds__(256) void cast_x_kernel(const float* __restrict__ src,
                                                     unsigned short* __restrict__ dst,
                                                     int n4) {
  int i = blockIdx.x * 256 + threadIdx.x;
  if (i >= n4) return;
  f32x4 v = reinterpret_cast<const f32x4*>(src)[i];
  us4 o;
#pragma unroll
  for (int j = 0; j < 4; ++j) o[j] = f2bf(v[j]);
  reinterpret_cast<us4*>(dst)[i] = o;
}

// ------------- transpose + cast: W [K][N] fp32 -> W^T [N][K] bf16 -------------
__global__ __launch_bounds__(256) void transpose_cast_kernel(const float* __restrict__ src,
                                                             unsigned short* __restrict__ dst,
                                                             int ldsrc, int lddst) {
  __shared__ float tile[32][33];
  int n0 = blockIdx.x * 32, k0 = blockIdx.y * 32;
  int tx = threadIdx.x, ty = threadIdx.y;  // block (32,8)
#pragma unroll
  for (int r = 0; r < 4; ++r)
    tile[ty + r * 8][tx] = src[(size_t)(k0 + ty + r * 8) * ldsrc + n0 + tx];
  __syncthreads();
#pragma unroll
  for (int r = 0; r < 4; ++r)
    dst[(size_t)(n0 + ty + r * 8) * lddst + k0 + tx] = f2bf(tile[tx][ty + r * 8]);
}

// ---------------- RoPE table: cos/sin [T][32] fp32 ----------------
__global__ __launch_bounds__(256) void rope_table_kernel(float* __restrict__ cost,
                                                         float* __restrict__ sint) {
  int idx = blockIdx.x * 256 + threadIdx.x;  // 2048*32
  int t = idx >> 5, j = idx & 31;
  double invf = pow(10000.0, -(double)j / 32.0);
  double ang = (double)t * invf;
  cost[idx] = (float)cos(ang);
  sint[idx] = (float)sin(ang);
}

// ---------------- GEMM: C[M][N] = A[M][K] * B^T[N][K], bf16 in, fp32 acc ----
// m97-family structure, BK=64 (halves barrier-drain count vs BK=32), LINEAR
// LDS staged via global_load_lds width=16. XOR col-block swizzle applied on
// BOTH sides (rule 21): global source col-block scb = (lane&7)^(lane>>3),
// fragment read col-block cb^(row&7) -> bank-balanced ds_read_b128.
// MODE 1: qkv epilogue with RoPE, fragment-major outputs
//   QF/KF[bh][blk32][ks][lane][8], VF[bh][t64][dgrp][ks][lane][8].
// MODE 0: plain fp32 store to out[M][N].
template <int MODE>
__global__ __launch_bounds__(256) void gemm_kernel(
    const unsigned short* __restrict__ A, const unsigned short* __restrict__ Bt,
    int M, int N, int K,
    unsigned short* __restrict__ qo, unsigned short* __restrict__ ko,
    unsigned short* __restrict__ vTo, const float* __restrict__ cost,
    const float* __restrict__ sint, float* __restrict__ out) {
  __shared__ __align__(16) unsigned short As[128 * 64];  // linear [row][64], 16KB
  __shared__ __align__(16) unsigned short Bs[128 * 64];
  const int tid = threadIdx.x;
  const int lane = tid & 63;
  const int wave = tid >> 6;
  const int wr = wave >> 1, wc = wave & 1;
  const int m0 = blockIdx.y * 128, n0 = blockIdx.x * 128;
  const int lrow = lane & 15, lhi = lane >> 4;
  // staging: chunk = 8 rows x 128B; wave does chunks wave*4..wave*4+3 per matrix.
  // LDS dest linear (chunk*1024B + lane*16B); global source col-block swizzled.
  const int srow = lane >> 3;               // row within chunk (0..7) = row&7
  const int scol = (((lane & 7) ^ srow) * 8);  // swizzled source col (elems)

  f32x4 zero4 = {0.f, 0.f, 0.f, 0.f};
  f32x4 acc[4][4];
#pragma unroll
  for (int mi = 0; mi < 4; ++mi)
#pragma unroll
    for (int ni = 0; ni < 4; ++ni) acc[mi][ni] = zero4;

  for (int kt = 0; kt < K; kt += 64) {
#pragma unroll
    for (int c2 = 0; c2 < 4; ++c2) {
      const int c = wave * 4 + c2;  // chunk 0..15
      GLOAD_LDS(&A[(size_t)(m0 + c * 8 + srow) * K + kt + scol], &As[c * 512]);
      GLOAD_LDS(&Bt[(size_t)(n0 + c * 8 + srow) * K + kt + scol], &Bs[c * 512]);
    }
    __syncthreads();  // drains vmcnt (global_load_lds) before frag reads
#pragma unroll
    for (int kk = 0; kk < 2; ++kk) {
      bf16x8 af[4], bfv[4];
#pragma unroll
      for (int i = 0; i < 4; ++i) {
        const int ra = wr * 64 + i * 16 + lrow;
        const int rb = wc * 64 + i * 16 + lrow;
        const int cba = (kk * 4 + lhi) ^ (ra & 7);  // un-swizzle on read
        const int cbb = (kk * 4 + lhi) ^ (rb & 7);
        af[i] = *reinterpret_cast<const bf16x8*>(&As[ra * 64 + cba * 8]);
        bfv[i] = *reinterpret_cast<const bf16x8*>(&Bs[rb * 64 + cbb * 8]);
      }
#pragma unroll
      for (int mi = 0; mi < 4; ++mi)
#pragma unroll
        for (int ni = 0; ni < 4; ++ni)
          acc[mi][ni] =
              __builtin_amdgcn_mfma_f32_16x16x32_bf16(af[mi], bfv[ni], acc[mi][ni], 0, 0, 0);
    }
    __syncthreads();  // all reads done before next stage overwrites
  }

  if (MODE == 0) {
#pragma unroll
    for (int mi = 0; mi < 4; ++mi)
#pragma unroll
      for (int ni = 0; ni < 4; ++ni) {
        int n = n0 + wc * 64 + ni * 16 + lrow;
#pragma unroll
        for (int r = 0; r < 4; ++r) {
          int m = m0 + wr * 64 + mi * 16 + lhi * 4 + r;
          out[(size_t)m * N + n] = acc[mi][ni][r];
        }
      }
  } else {
#pragma unroll
    for (int mi = 0; mi < 4; ++mi) {
      int mb = m0 + wr * 64 + mi * 16 + lhi * 4;  // 4 consecutive rows (t)
      int b = mb >> 11, tb = mb & (T_SEQ - 1);
#pragma unroll
      for (int ni = 0; ni < 4; ++ni) {
        int n = n0 + wc * 64 + ni * 16 + lrow;
        int sec = n >> 10;          // 0=q 1=k 2=v
        int h = (n >> 6) & 15;
        int d = n & 63;
        int bh_ = b * NH + h;
        if (sec == 2) {
          int t64 = tb >> 6, ks = (tb >> 4) & 3, hiv = (tb >> 3) & 1, e0 = tb & 7;
          int dgrp = d >> 5, lanev = hiv * 32 + (d & 31);
          us4 pk;
#pragma unroll
          for (int r = 0; r < 4; ++r) pk[r] = f2bf(acc[mi][ni][r]);
          size_t addr =
              ((((size_t)bh_ * 32 + t64) * 2 + dgrp) * 4 + ks) * 512 + lanev * 8 + e0;
          *reinterpret_cast<us4*>(&vTo[addr]) = pk;
        } else {
          int dm = d & 31;
          float sgn = (d < 32) ? -1.0f : 1.0f;
          unsigned short* dstp = (sec == 0) ? qo : ko;
          int ks = d >> 4, hiq = (d >> 3) & 1, e = d & 7;
#pragma unroll
          for (int r = 0; r < 4; ++r) {
            int t = tb + r;
            float c = cost[t * 32 + dm], s = sint[t * 32 + dm];
            float val = acc[mi][ni][r] * c + sgn * acc[mi][ni ^ 2][r] * s;
            if (sec == 0) val *= 0.125f;  // 1/sqrt(64) folded into q
            int blk = t >> 5, lane_ = hiq * 32 + (t & 31);
            dstp[(((size_t)bh_ * 64 + blk) * 4 + ks) * 512 + lane_ * 8 + e] = f2bf(val);
          }
        }
      }
    }
  }
}

// ---------------- flash attention, causal; 32x32 swapped-QK^T ----------------
// EXACT per-wave balance: wave owns q-blocks {p, 63-p}; myt(pos)=pos/2+1 so
// every wave processes exactly 33 kv-tiles -> no drain tail. 512 blocks
// (2/CU, 8 waves/CU). Register double-buffered K prefetch + early V issue.
// Fragment-major layouts (coalesced). In-register softmax; T13 defer-max;
// setprio around MFMA clusters.
__global__ __launch_bounds__(256, 2) void attn_kernel(const unsigned short* __restrict__ qg,
                                                      const unsigned short* __restrict__ kg,
                                                      const unsigned short* __restrict__ vtg,
                                                      unsigned short* __restrict__ att) {
  __shared__ __align__(16) unsigned short P[4][32][72];  // per-wave P buffer
  const int tid = threadIdx.x;
  const int lane = tid & 63;
  const int w = tid >> 6;
  const int l31 = lane & 31, hi = lane >> 5;
  const int bid = (int)blockIdx.x;
  const int xcd = bid & 7, j = bid >> 3;        // j 0..63
  const int bh = xcd * 8 + (j >> 3);            // 8 blocks per head
  const int p = (j & 7) * 4 + w;                // pair index 0..31
  const unsigned short* qfp = qg + (size_t)bh * 131072;
  const unsigned short* kfp = kg + (size_t)bh * 131072;
  const unsigned short* vfp = vtg + (size_t)bh * 131072;
  const int b = bh >> 4, h = bh & 15;

  auto run_pos = [&](int pos) {
    const int qrow = pos * 32 + l31;
    bf16x8 qf[4];
#pragma unroll
    for (int ks = 0; ks < 4; ++ks)
      qf[ks] =
          *reinterpret_cast<const bf16x8*>(&qfp[((size_t)pos * 4 + ks) * 512 + lane * 8]);
    f32x16 oA = zero16(), oB = zero16();
    float mrun = -3.0e38f, lrun = 0.0f;
    const int myt = (pos >> 1) + 1;

    bf16x8 kA0[4], kB0[4], kA1[4], kB1[4];
#pragma unroll
    for (int ks = 0; ks < 4; ++ks) {  // preload K tile 0
      kA0[ks] = *reinterpret_cast<const bf16x8*>(&kfp[(size_t)(0 + ks) * 512 + lane * 8]);
      kB0[ks] = *reinterpret_cast<const bf16x8*>(&kfp[(size_t)(4 + ks) * 512 + lane * 8]);
    }

    auto step = [&](int t, bf16x8 (&kcA)[4], bf16x8 (&kcB)[4], bf16x8 (&knA)[4],
                    bf16x8 (&knB)[4]) {
      // early V issue: consumed only after softmax -> latency hidden
      bf16x8 vA[4], vB[4];
#pragma unroll
      for (int ks = 0; ks < 4; ++ks) {
        vA[ks] = *reinterpret_cast<const bf16x8*>(
            &vfp[((size_t)(2 * t) * 4 + ks) * 512 + lane * 8]);
        vB[ks] = *reinterpret_cast<const bf16x8*>(
            &vfp[((size_t)(2 * t + 1) * 4 + ks) * 512 + lane * 8]);
      }
      // QK^T with current K (prefetched last iteration)
      f32x16 sA = zero16(), sB = zero16();
      __builtin_amdgcn_s_setprio(1);
#pragma unroll
      for (int ks = 0; ks < 4; ++ks) {
        sA = __builtin_amdgcn_mfma_f32_32x32x16_bf16(kcA[ks], qf[ks], sA, 0, 0, 0);
        sB = __builtin_amdgcn_mfma_f32_32x32x16_bf16(kcB[ks], qf[ks], sB, 0, 0, 0);
      }
      __builtin_amdgcn_s_setprio(0);
      // prefetch next K tile (used next iteration; hides under softmax+PV)
      if (t + 1 < myt) {
#pragma unroll
        for (int ks = 0; ks < 4; ++ks) {
          knA[ks] = *reinterpret_cast<const bf16x8*>(
              &kfp[((size_t)(2 * t + 2) * 4 + ks) * 512 + lane * 8]);
          knB[ks] = *reinterpret_cast<const bf16x8*>(
              &kfp[((size_t)(2 * t + 3) * 4 + ks) * 512 + lane * 8]);
        }
      }
      // causal mask (only final tile can contain future keys)
      if (t == myt - 1) {
        const int kvb = t * 64;
#pragma unroll
        for (int r = 0; r < 16; ++r) {
          int keyA = kvb + (r & 3) + 8 * (r >> 2) + 4 * hi;
          if (keyA > qrow) sA[r] = -1e30f;
          if (keyA + 32 > qrow) sB[r] = -1e30f;
        }
      }
      // in-register online softmax (per-lane scalars)
      float tr[16];
#pragma unroll
      for (int i = 0; i < 16; ++i) tr[i] = fmaxf(sA[i], sB[i]);
#pragma unroll
      for (int i = 0; i < 8; ++i) tr[i] = fmaxf(tr[i], tr[i + 8]);
#pragma unroll
      for (int i = 0; i < 4; ++i) tr[i] = fmaxf(tr[i], tr[i + 4]);
      float tm = fmaxf(fmaxf(tr[0], tr[1]), fmaxf(tr[2], tr[3]));
      tm = fmaxf(tm, __shfl_xor(tm, 32));  // merge lane halves (same query)
      // T13 defer-max: only rescale when max grew by > 8
      if (!__all(tm - mrun <= 8.0f)) {
        float mnew = fmaxf(mrun, tm);
        float alpha = __expf(mrun - mnew);
        lrun *= alpha;
#pragma unroll
        for (int i = 0; i < 16; ++i) {
          oA[i] *= alpha;
          oB[i] *= alpha;
        }
        mrun = mnew;
      }
#pragma unroll
      for (int i = 0; i < 16; ++i) {
        sA[i] = __expf(sA[i] - mrun);
        sB[i] = __expf(sB[i] - mrun);
      }
      float sr[16];
#pragma unroll
      for (int i = 0; i < 16; ++i) sr[i] = sA[i] + sB[i];
#pragma unroll
      for (int i = 0; i < 8; ++i) sr[i] += sr[i + 8];
#pragma unroll
      for (int i = 0; i < 4; ++i) sr[i] += sr[i + 4];
      float lsum = (sr[0] + sr[1]) + (sr[2] + sr[3]);
      lsum += __shfl_xor(lsum, 32);
      lrun += lsum;
      // P: S-layout -> [q][key] via per-wave LDS (no barrier needed)
#pragma unroll
      for (int g = 0; g < 4; ++g) {
        us4 pa, pb;
#pragma unroll
        for (int jj = 0; jj < 4; ++jj) {
          pa[jj] = f2bf(sA[4 * g + jj]);
          pb[jj] = f2bf(sB[4 * g + jj]);
        }
        *reinterpret_cast<us4*>(&P[w][l31][g * 8 + 4 * hi]) = pa;
        *reinterpret_cast<us4*>(&P[w][l31][32 + g * 8 + 4 * hi]) = pb;
      }
      // PV: O^T += mfma(V^T, P)
      __builtin_amdgcn_s_setprio(1);
#pragma unroll
      for (int ks = 0; ks < 4; ++ks) {
        bf16x8 pf = *reinterpret_cast<const bf16x8*>(&P[w][l31][ks * 16 + hi * 8]);
        oA = __builtin_amdgcn_mfma_f32_32x32x16_bf16(vA[ks], pf, oA, 0, 0, 0);
        oB = __builtin_amdgcn_mfma_f32_32x32x16_bf16(vB[ks], pf, oB, 0, 0, 0);
      }
      __builtin_amdgcn_s_setprio(0);
    };

    int t = 0;
    while (t < myt) {
      step(t, kA0, kB0, kA1, kB1);
      ++t;
      if (t >= myt) break;
      step(t, kA1, kB1, kA0, kB0);
      ++t;
    }

    const float inv = 1.0f / lrun;
    const size_t obase = ((size_t)b * T_SEQ + qrow) * CDIM + h * HD;
#pragma unroll
    for (int g = 0; g < 4; ++g) {
      us4 pa, pb;
#pragma unroll
      for (int jj = 0; jj < 4; ++jj) {
        pa[jj] = f2bf(oA[4 * g + jj] * inv);
        pb[jj] = f2bf(oB[4 * g + jj] * inv);
      }
      *reinterpret_cast<us4*>(&att[obase + g * 8 + 4 * hi]) = pa;
      *reinterpret_cast<us4*>(&att[obase + 32 + g * 8 + 4 * hi]) = pb;
    }
  };

  run_pos(63 - p);  // heavy half first (streams K/V, warms L2 for light half)
  run_pos(p);       // light half re-reads an L2-hot prefix
}

extern "C" void kernel_launch(void* const* d_in, const int* in_sizes, int n_in,
                              void* d_out, int out_size, void* d_ws, size_t ws_size,
                              hipStream_t stream) {
  const float* x = (const float*)d_in[0];
  const float* Wq = (const float*)d_in[1];
  const float* Wkv = (const float*)d_in[2];
  const float* Wc = (const float*)d_in[3];
  float* out = (float*)d_out;

  char* ws = (char*)d_ws;
  size_t off = 0;
  auto alloc = [&](size_t bytes) {
    void* p = ws + off;
    off += (bytes + 255) & ~(size_t)255;
    return p;
  };
  const size_t NTOK = 4ull * T_SEQ;            // 8192
  const size_t NELEM = NTOK * CDIM;            // 8388608
  unsigned short* xb = (unsigned short*)alloc(NELEM * 2);   // also reused for att
  unsigned short* WT = (unsigned short*)alloc(3072ull * 1024 * 2);
  unsigned short* WcT = (unsigned short*)alloc(1024ull * 1024 * 2);
  unsigned short* qb = (unsigned short*)alloc(NELEM * 2);
  unsigned short* kb = (unsigned short*)alloc(NELEM * 2);
  unsigned short* vT = (unsigned short*)alloc(NELEM * 2);
  float* cost = (float*)alloc(T_SEQ * 32 * 4);
  float* sint = (float*)alloc(T_SEQ * 32 * 4);
  unsigned short* att = xb;  // xb dead after gemm<1>; reuse for attention output

  cast_x_kernel<<<(int)(NELEM / 4 / 256), 256, 0, stream>>>(x, xb, (int)(NELEM / 4));
  transpose_cast_kernel<<<dim3(32, 32), dim3(32, 8), 0, stream>>>(Wq, WT, 1024, 1024);
  transpose_cast_kernel<<<dim3(64, 32), dim3(32, 8), 0, stream>>>(Wkv, WT + 1024 * 1024, 2048,
                                                                  1024);
  transpose_cast_kernel<<<dim3(32, 32), dim3(32, 8), 0, stream>>>(Wc, WcT, 1024, 1024);
  rope_table_kernel<<<T_SEQ * 32 / 256, 256, 0, stream>>>(cost, sint);

  gemm_kernel<1><<<dim3(3072 / 128, NTOK / 128), 256, 0, stream>>>(
      xb, WT, (int)NTOK, 3072, 1024, qb, kb, vT, cost, sint, nullptr);

  attn_kernel<<<dim3(512), 256, 0, stream>>>(qb, kb, vT, att);

  gemm_kernel<0><<<dim3(1024 / 128, NTOK / 128), 256, 0, stream>>>(
      att, WcT, (int)NTOK, 1024, 1024, nullptr, nullptr, nullptr, nullptr, nullptr, out);
}

// Round 9
// 174.760 us; speedup vs baseline: 1.4648x; 1.0769x over previous
//
#include <hip/hip_runtime.h>
#include <math.h>

typedef __attribute__((ext_vector_type(4))) float f32x4;
typedef __attribute__((ext_vector_type(16))) float f32x16;
typedef __attribute__((ext_vector_type(8))) short bf16x8;
typedef __attribute__((ext_vector_type(4))) unsigned short us4;

#define T_SEQ 2048
#define NH 16
#define HD 64
#define CDIM 1024

__device__ __forceinline__ unsigned short f2bf(float f) {
  unsigned int u = __float_as_uint(f);
  u += 0x7fffu + ((u >> 16) & 1u);
  return (unsigned short)(u >> 16);
}

__device__ __forceinline__ f32x16 zero16() {
  f32x16 z;
#pragma unroll
  for (int i = 0; i < 16; ++i) z[i] = 0.0f;
  return z;
}

// global -> LDS direct (16B/lane, wave-uniform LDS base + lane*16)
#define GLOAD_LDS(g, l)                                                   \
  __builtin_amdgcn_global_load_lds(                                       \
      (const __attribute__((address_space(1))) unsigned int*)(g),         \
      (__attribute__((address_space(3))) unsigned int*)(l), 16, 0, 0)

// ---------------- cast x: fp32 -> bf16 ----------------
__global__ __launch_bounds__(256) void cast_x_kernel(const float* __restrict__ src,
                                                     unsigned short* __restrict__ dst,
                                                     int n4) {
  int i = blockIdx.x * 256 + threadIdx.x;
  if (i >= n4) return;
  f32x4 v = reinterpret_cast<const f32x4*>(src)[i];
  us4 o;
#pragma unroll
  for (int j = 0; j < 4; ++j) o[j] = f2bf(v[j]);
  reinterpret_cast<us4*>(dst)[i] = o;
}

// ------------- transpose + cast: W [K][N] fp32 -> W^T [N][K] bf16 -------------
__global__ __launch_bounds__(256) void transpose_cast_kernel(const float* __restrict__ src,
                                                             unsigned short* __restrict__ dst,
                                                             int ldsrc, int lddst) {
  __shared__ float tile[32][33];
  int n0 = blockIdx.x * 32, k0 = blockIdx.y * 32;
  int tx = threadIdx.x, ty = threadIdx.y;  // block (32,8)
#pragma unroll
  for (int r = 0; r < 4; ++r)
    tile[ty + r * 8][tx] = src[(size_t)(k0 + ty + r * 8) * ldsrc + n0 + tx];
  __syncthreads();
#pragma unroll
  for (int r = 0; r < 4; ++r)
    dst[(size_t)(n0 + ty + r * 8) * lddst + k0 + tx] = f2bf(tile[tx][ty + r * 8]);
}

// ---------------- RoPE table: cos/sin [T][32] fp32 ----------------
__global__ __launch_bounds__(256) void rope_table_kernel(float* __restrict__ cost,
                                                         float* __restrict__ sint) {
  int idx = blockIdx.x * 256 + threadIdx.x;  // 2048*32
  int t = idx >> 5, j = idx & 31;
  double invf = pow(10000.0, -(double)j / 32.0);
  double ang = (double)t * invf;
  cost[idx] = (float)cos(ang);
  sint[idx] = (float)sin(ang);
}

// ---------------- GEMM: C[M][N] = A[M][K] * B^T[N][K], bf16 in, fp32 acc ----
// 2-phase double-buffered pipeline (T3 minimum recipe): STAGE next K-tile via
// global_load_lds BEFORE computing current tile; ONE __syncthreads per tile
// (its vmcnt(0) lands after MFMA covered the load flight). BK=64, 2x32KB LDS.
// XOR col-block swizzle both-sides (rule 21): source scb=(lane&7)^(lane>>3),
// read cb^(row&7) -> 0 bank conflicts (verified R8).
// MODE 1: qkv epilogue with RoPE, fragment-major outputs
//   QF/KF[bh][blk32][ks][lane][8], VF[bh][t64][dgrp][ks][lane][8].
// MODE 0: plain fp32 store to out[M][N].
template <int MODE>
__global__ __launch_bounds__(256) void gemm_kernel(
    const unsigned short* __restrict__ A, const unsigned short* __restrict__ Bt,
    int M, int N, int K,
    unsigned short* __restrict__ qo, unsigned short* __restrict__ ko,
    unsigned short* __restrict__ vTo, const float* __restrict__ cost,
    const float* __restrict__ sint, float* __restrict__ out) {
  __shared__ __align__(16) unsigned short As[2][128 * 64];  // 2 x 16KB
  __shared__ __align__(16) unsigned short Bs[2][128 * 64];  // 2 x 16KB
  const int tid = threadIdx.x;
  const int lane = tid & 63;
  const int wave = tid >> 6;
  const int wr = wave >> 1, wc = wave & 1;
  const int m0 = blockIdx.y * 128, n0 = blockIdx.x * 128;
  const int lrow = lane & 15, lhi = lane >> 4;
  const int srow = lane >> 3;                  // row within 8-row chunk
  const int scol = (((lane & 7) ^ srow) * 8);  // swizzled source col (elems)

  f32x4 zero4 = {0.f, 0.f, 0.f, 0.f};
  f32x4 acc[4][4];
#pragma unroll
  for (int mi = 0; mi < 4; ++mi)
#pragma unroll
    for (int ni = 0; ni < 4; ++ni) acc[mi][ni] = zero4;

  const int ntiles = K >> 6;  // BK=64
  auto stage = [&](int bf, int kt) {
#pragma unroll
    for (int c2 = 0; c2 < 4; ++c2) {
      const int c = wave * 4 + c2;  // chunk 0..15 (8 rows x 128B each)
      GLOAD_LDS(&A[(size_t)(m0 + c * 8 + srow) * K + kt + scol], &As[bf][c * 512]);
      GLOAD_LDS(&Bt[(size_t)(n0 + c * 8 + srow) * K + kt + scol], &Bs[bf][c * 512]);
    }
  };

  stage(0, 0);
  __syncthreads();  // buf0 ready
  int cur = 0;
  for (int ti = 0; ti < ntiles; ++ti) {
    if (ti + 1 < ntiles) stage(cur ^ 1, (ti + 1) * 64);  // issue early: in flight under compute
#pragma unroll
    for (int kk = 0; kk < 2; ++kk) {
      bf16x8 af[4], bfv[4];
#pragma unroll
      for (int i = 0; i < 4; ++i) {
        const int ra = wr * 64 + i * 16 + lrow;
        const int rb = wc * 64 + i * 16 + lrow;
        const int cba = (kk * 4 + lhi) ^ (ra & 7);  // un-swizzle on read
        const int cbb = (kk * 4 + lhi) ^ (rb & 7);
        af[i] = *reinterpret_cast<const bf16x8*>(&As[cur][ra * 64 + cba * 8]);
        bfv[i] = *reinterpret_cast<const bf16x8*>(&Bs[cur][rb * 64 + cbb * 8]);
      }
#pragma unroll
      for (int mi = 0; mi < 4; ++mi)
#pragma unroll
        for (int ni = 0; ni < 4; ++ni)
          acc[mi][ni] =
              __builtin_amdgcn_mfma_f32_16x16x32_bf16(af[mi], bfv[ni], acc[mi][ni], 0, 0, 0);
    }
    __syncthreads();  // drains my gloads (short wait: flew under MFMA) + reads; swap safe
    cur ^= 1;
  }

  if (MODE == 0) {
#pragma unroll
    for (int mi = 0; mi < 4; ++mi)
#pragma unroll
      for (int ni = 0; ni < 4; ++ni) {
        int n = n0 + wc * 64 + ni * 16 + lrow;
#pragma unroll
        for (int r = 0; r < 4; ++r) {
          int m = m0 + wr * 64 + mi * 16 + lhi * 4 + r;
          out[(size_t)m * N + n] = acc[mi][ni][r];
        }
      }
  } else {
#pragma unroll
    for (int mi = 0; mi < 4; ++mi) {
      int mb = m0 + wr * 64 + mi * 16 + lhi * 4;  // 4 consecutive rows (t)
      int b = mb >> 11, tb = mb & (T_SEQ - 1);
#pragma unroll
      for (int ni = 0; ni < 4; ++ni) {
        int n = n0 + wc * 64 + ni * 16 + lrow;
        int sec = n >> 10;          // 0=q 1=k 2=v
        int h = (n >> 6) & 15;
        int d = n & 63;
        int bh_ = b * NH + h;
        if (sec == 2) {
          int t64 = tb >> 6, ks = (tb >> 4) & 3, hiv = (tb >> 3) & 1, e0 = tb & 7;
          int dgrp = d >> 5, lanev = hiv * 32 + (d & 31);
          us4 pk;
#pragma unroll
          for (int r = 0; r < 4; ++r) pk[r] = f2bf(acc[mi][ni][r]);
          size_t addr =
              ((((size_t)bh_ * 32 + t64) * 2 + dgrp) * 4 + ks) * 512 + lanev * 8 + e0;
          *reinterpret_cast<us4*>(&vTo[addr]) = pk;
        } else {
          int dm = d & 31;
          float sgn = (d < 32) ? -1.0f : 1.0f;
          unsigned short* dstp = (sec == 0) ? qo : ko;
          int ks = d >> 4, hiq = (d >> 3) & 1, e = d & 7;
#pragma unroll
          for (int r = 0; r < 4; ++r) {
            int t = tb + r;
            float c = cost[t * 32 + dm], s = sint[t * 32 + dm];
            float val = acc[mi][ni][r] * c + sgn * acc[mi][ni ^ 2][r] * s;
            if (sec == 0) val *= 0.125f;  // 1/sqrt(64) folded into q
            int blk = t >> 5, lane_ = hiq * 32 + (t & 31);
            dstp[(((size_t)bh_ * 64 + blk) * 4 + ks) * 512 + lane_ * 8 + e] = f2bf(val);
          }
        }
      }
    }
  }
}

// ---------------- flash attention, causal; 32x32 swapped-QK^T ----------------
// EXACT per-wave balance: wave owns q-blocks {p, 63-p}; myt(pos)=pos/2+1 so
// every wave processes exactly 33 kv-tiles -> no drain tail. 512 blocks
// (2/CU, 8 waves/CU). Register double-buffered K prefetch + early V issue.
// Fragment-major layouts (coalesced). In-register softmax; T13 defer-max;
// setprio around MFMA clusters.
__global__ __launch_bounds__(256, 2) void attn_kernel(const unsigned short* __restrict__ qg,
                                                      const unsigned short* __restrict__ kg,
                                                      const unsigned short* __restrict__ vtg,
                                                      unsigned short* __restrict__ att) {
  __shared__ __align__(16) unsigned short P[4][32][72];  // per-wave P buffer
  const int tid = threadIdx.x;
  const int lane = tid & 63;
  const int w = tid >> 6;
  const int l31 = lane & 31, hi = lane >> 5;
  const int bid = (int)blockIdx.x;
  const int xcd = bid & 7, j = bid >> 3;        // j 0..63
  const int bh = xcd * 8 + (j >> 3);            // 8 blocks per head
  const int p = (j & 7) * 4 + w;                // pair index 0..31
  const unsigned short* qfp = qg + (size_t)bh * 131072;
  const unsigned short* kfp = kg + (size_t)bh * 131072;
  const unsigned short* vfp = vtg + (size_t)bh * 131072;
  const int b = bh >> 4, h = bh & 15;

  auto run_pos = [&](int pos) {
    const int qrow = pos * 32 + l31;
    bf16x8 qf[4];
#pragma unroll
    for (int ks = 0; ks < 4; ++ks)
      qf[ks] =
          *reinterpret_cast<const bf16x8*>(&qfp[((size_t)pos * 4 + ks) * 512 + lane * 8]);
    f32x16 oA = zero16(), oB = zero16();
    float mrun = -3.0e38f, lrun = 0.0f;
    const int myt = (pos >> 1) + 1;

    bf16x8 kA0[4], kB0[4], kA1[4], kB1[4];
#pragma unroll
    for (int ks = 0; ks < 4; ++ks) {  // preload K tile 0
      kA0[ks] = *reinterpret_cast<const bf16x8*>(&kfp[(size_t)(0 + ks) * 512 + lane * 8]);
      kB0[ks] = *reinterpret_cast<const bf16x8*>(&kfp[(size_t)(4 + ks) * 512 + lane * 8]);
    }

    auto step = [&](int t, bf16x8 (&kcA)[4], bf16x8 (&kcB)[4], bf16x8 (&knA)[4],
                    bf16x8 (&knB)[4]) {
      // early V issue: consumed only after softmax -> latency hidden
      bf16x8 vA[4], vB[4];
#pragma unroll
      for (int ks = 0; ks < 4; ++ks) {
        vA[ks] = *reinterpret_cast<const bf16x8*>(
            &vfp[((size_t)(2 * t) * 4 + ks) * 512 + lane * 8]);
        vB[ks] = *reinterpret_cast<const bf16x8*>(
            &vfp[((size_t)(2 * t + 1) * 4 + ks) * 512 + lane * 8]);
      }
      // QK^T with current K (prefetched last iteration)
      f32x16 sA = zero16(), sB = zero16();
      __builtin_amdgcn_s_setprio(1);
#pragma unroll
      for (int ks = 0; ks < 4; ++ks) {
        sA = __builtin_amdgcn_mfma_f32_32x32x16_bf16(kcA[ks], qf[ks], sA, 0, 0, 0);
        sB = __builtin_amdgcn_mfma_f32_32x32x16_bf16(kcB[ks], qf[ks], sB, 0, 0, 0);
      }
      __builtin_amdgcn_s_setprio(0);
      // prefetch next K tile (used next iteration; hides under softmax+PV)
      if (t + 1 < myt) {
#pragma unroll
        for (int ks = 0; ks < 4; ++ks) {
          knA[ks] = *reinterpret_cast<const bf16x8*>(
              &kfp[((size_t)(2 * t + 2) * 4 + ks) * 512 + lane * 8]);
          knB[ks] = *reinterpret_cast<const bf16x8*>(
              &kfp[((size_t)(2 * t + 3) * 4 + ks) * 512 + lane * 8]);
        }
      }
      // causal mask (only final tile can contain future keys)
      if (t == myt - 1) {
        const int kvb = t * 64;
#pragma unroll
        for (int r = 0; r < 16; ++r) {
          int keyA = kvb + (r & 3) + 8 * (r >> 2) + 4 * hi;
          if (keyA > qrow) sA[r] = -1e30f;
          if (keyA + 32 > qrow) sB[r] = -1e30f;
        }
      }
      // in-register online softmax (per-lane scalars)
      float tr[16];
#pragma unroll
      for (int i = 0; i < 16; ++i) tr[i] = fmaxf(sA[i], sB[i]);
#pragma unroll
      for (int i = 0; i < 8; ++i) tr[i] = fmaxf(tr[i], tr[i + 8]);
#pragma unroll
      for (int i = 0; i < 4; ++i) tr[i] = fmaxf(tr[i], tr[i + 4]);
      float tm = fmaxf(fmaxf(tr[0], tr[1]), fmaxf(tr[2], tr[3]));
      tm = fmaxf(tm, __shfl_xor(tm, 32));  // merge lane halves (same query)
      // T13 defer-max: only rescale when max grew by > 8
      if (!__all(tm - mrun <= 8.0f)) {
        float mnew = fmaxf(mrun, tm);
        float alpha = __expf(mrun - mnew);
        lrun *= alpha;
#pragma unroll
        for (int i = 0; i < 16; ++i) {
          oA[i] *= alpha;
          oB[i] *= alpha;
        }
        mrun = mnew;
      }
#pragma unroll
      for (int i = 0; i < 16; ++i) {
        sA[i] = __expf(sA[i] - mrun);
        sB[i] = __expf(sB[i] - mrun);
      }
      float sr[16];
#pragma unroll
      for (int i = 0; i < 16; ++i) sr[i] = sA[i] + sB[i];
#pragma unroll
      for (int i = 0; i < 8; ++i) sr[i] += sr[i + 8];
#pragma unroll
      for (int i = 0; i < 4; ++i) sr[i] += sr[i + 4];
      float lsum = (sr[0] + sr[1]) + (sr[2] + sr[3]);
      lsum += __shfl_xor(lsum, 32);
      lrun += lsum;
      // P: S-layout -> [q][key] via per-wave LDS (no barrier needed)
#pragma unroll
      for (int g = 0; g < 4; ++g) {
        us4 pa, pb;
#pragma unroll
        for (int jj = 0; jj < 4; ++jj) {
          pa[jj] = f2bf(sA[4 * g + jj]);
          pb[jj] = f2bf(sB[4 * g + jj]);
        }
        *reinterpret_cast<us4*>(&P[w][l31][g * 8 + 4 * hi]) = pa;
        *reinterpret_cast<us4*>(&P[w][l31][32 + g * 8 + 4 * hi]) = pb;
      }
      // PV: O^T += mfma(V^T, P)
      __builtin_amdgcn_s_setprio(1);
#pragma unroll
      for (int ks = 0; ks < 4; ++ks) {
        bf16x8 pf = *reinterpret_cast<const bf16x8*>(&P[w][l31][ks * 16 + hi * 8]);
        oA = __builtin_amdgcn_mfma_f32_32x32x16_bf16(vA[ks], pf, oA, 0, 0, 0);
        oB = __builtin_amdgcn_mfma_f32_32x32x16_bf16(vB[ks], pf, oB, 0, 0, 0);
      }
      __builtin_amdgcn_s_setprio(0);
    };

    int t = 0;
    while (t < myt) {
      step(t, kA0, kB0, kA1, kB1);
      ++t;
      if (t >= myt) break;
      step(t, kA1, kB1, kA0, kB0);
      ++t;
    }

    const float inv = 1.0f / lrun;
    const size_t obase = ((size_t)b * T_SEQ + qrow) * CDIM + h * HD;
#pragma unroll
    for (int g = 0; g < 4; ++g) {
      us4 pa, pb;
#pragma unroll
      for (int jj = 0; jj < 4; ++jj) {
        pa[jj] = f2bf(oA[4 * g + jj] * inv);
        pb[jj] = f2bf(oB[4 * g + jj] * inv);
      }
      *reinterpret_cast<us4*>(&att[obase + g * 8 + 4 * hi]) = pa;
      *reinterpret_cast<us4*>(&att[obase + 32 + g * 8 + 4 * hi]) = pb;
    }
  };

  run_pos(63 - p);  // heavy half first (streams K/V, warms L2 for light half)
  run_pos(p);       // light half re-reads an L2-hot prefix
}

extern "C" void kernel_launch(void* const* d_in, const int* in_sizes, int n_in,
                              void* d_out, int out_size, void* d_ws, size_t ws_size,
                              hipStream_t stream) {
  const float* x = (const float*)d_in[0];
  const float* Wq = (const float*)d_in[1];
  const float* Wkv = (const float*)d_in[2];
  const float* Wc = (const float*)d_in[3];
  float* out = (float*)d_out;

  char* ws = (char*)d_ws;
  size_t off = 0;
  auto alloc = [&](size_t bytes) {
    void* p = ws + off;
    off += (bytes + 255) & ~(size_t)255;
    return p;
  };
  const size_t NTOK = 4ull * T_SEQ;            // 8192
  const size_t NELEM = NTOK * CDIM;            // 8388608
  unsigned short* xb = (unsigned short*)alloc(NELEM * 2);   // also reused for att
  unsigned short* WT = (unsigned short*)alloc(3072ull * 1024 * 2);
  unsigned short* WcT = (unsigned short*)alloc(1024ull * 1024 * 2);
  unsigned short* qb = (unsigned short*)alloc(NELEM * 2);
  unsigned short* kb = (unsigned short*)alloc(NELEM * 2);
  unsigned short* vT = (unsigned short*)alloc(NELEM * 2);
  float* cost = (float*)alloc(T_SEQ * 32 * 4);
  float* sint = (float*)alloc(T_SEQ * 32 * 4);
  unsigned short* att = xb;  // xb dead after gemm<1>; reuse for attention output

  cast_x_kernel<<<(int)(NELEM / 4 / 256), 256, 0, stream>>>(x, xb, (int)(NELEM / 4));
  transpose_cast_kernel<<<dim3(32, 32), dim3(32, 8), 0, stream>>>(Wq, WT, 1024, 1024);
  transpose_cast_kernel<<<dim3(64, 32), dim3(32, 8), 0, stream>>>(Wkv, WT + 1024 * 1024, 2048,
                                                                  1024);
  transpose_cast_kernel<<<dim3(32, 32), dim3(32, 8), 0, stream>>>(Wc, WcT, 1024, 1024);
  rope_table_kernel<<<T_SEQ * 32 / 256, 256, 0, stream>>>(cost, sint);

  gemm_kernel<1><<<dim3(3072 / 128, NTOK / 128), 256, 0, stream>>>(
      xb, WT, (int)NTOK, 3072, 1024, qb, kb, vT, cost, sint, nullptr);

  attn_kernel<<<dim3(512), 256, 0, stream>>>(qb, kb, vT, att);

  gemm_kernel<0><<<dim3(1024 / 128, NTOK / 128), 256, 0, stream>>>(
      att, WcT, (int)NTOK, 1024, 1024, nullptr, nullptr, nullptr, nullptr, nullptr, out);
}